// Round 5
// baseline (185.860 us; speedup 1.0000x reference)
//
#include <hip/hip_runtime.h>

#define NF 36
#define QN 100
#define TN 20
#define CN 92
#define NB 64
#define BSTR 104   // ben/price pad; [100..103] = -INF / 0 sentinels

struct T2 { float v0, v1, p0; int i0; };

__global__ __launch_bounds__(64) void matcher_kernel(
    const float* __restrict__ logits,   // [64][3600][92]
    const float* __restrict__ pboxes,   // [64][3600][4]
    const int*   __restrict__ tlabels,  // [36][64][20]
    const float* __restrict__ tboxes,   // [36][64][20][4]
    float* __restrict__ out_cost,       // [64][36][100][20]
    float* __restrict__ out_pred,       // [64][36][20]
    float* __restrict__ out_tgt)        // [64][36][20]
{
    const int bf = blockIdx.x;          // b*36 + f
    const int b  = bf / NF;
    const int f  = bf % NF;
    const int lane = threadIdx.x;

    __shared__ __align__(16) float ben[TN][BSTR];  // benefit[t][q] = -cost[q][t]
    __shared__ __align__(16) float price[BSTR];
    __shared__ int   objl[TN];
    __shared__ int   slab[TN];
    __shared__ float tbr[TN][4];        // raw cxcywh
    __shared__ float tbx[TN][4];        // xyxy
    __shared__ float tarea[TN];

    // ---- stage targets ----
    if (lane < TN) {
        const int base = (f * NB + b) * TN + lane;
        slab[lane] = tlabels[base];
        const float* tb = tboxes + (size_t)base * 4;
        float cx = tb[0], cy = tb[1], w = tb[2], h = tb[3];
        tbr[lane][0] = cx; tbr[lane][1] = cy; tbr[lane][2] = w; tbr[lane][3] = h;
        float x1 = cx - 0.5f * w, y1 = cy - 0.5f * h;
        float x2 = cx + 0.5f * w, y2 = cy + 0.5f * h;
        tbx[lane][0] = x1; tbx[lane][1] = y1; tbx[lane][2] = x2; tbx[lane][3] = y2;
        tarea[lane] = (x2 - x1) * (y2 - y1);
    }
    __syncthreads();

    // ---- cost phase: register-resident logits, 2 passes over q ----
    float mn = INFINITY, mx = -INFINITY;
    for (int p = 0; p < 2; ++p) {
        const int q = lane + 64 * p;
        if (q < QN) {
            const size_t row = (size_t)b * (NF * QN) + (size_t)f * QN + q;
            const float* L = logits + row * CN;
            const float4* L4 = reinterpret_cast<const float4*>(L);
            float4 r[23];
            #pragma unroll
            for (int i = 0; i < 23; ++i) r[i] = L4[i];
            // sequential c-order max then exp-sum (bit-identical to passing kernels)
            float m = -INFINITY;
            #pragma unroll
            for (int i = 0; i < 23; ++i) {
                float4 v = r[i];
                m = fmaxf(m, v.x); m = fmaxf(m, v.y); m = fmaxf(m, v.z); m = fmaxf(m, v.w);
            }
            float s = 0.f;
            #pragma unroll
            for (int i = 0; i < 23; ++i) {
                float4 v = r[i];
                s += expf(v.x - m); s += expf(v.y - m); s += expf(v.z - m); s += expf(v.w - m);
            }

            float4 pbv = reinterpret_cast<const float4*>(pboxes)[row];
            float cx = pbv.x, cy = pbv.y, w = pbv.z, h = pbv.w;
            float px1 = cx - 0.5f * w, py1 = cy - 0.5f * h;
            float px2 = cx + 0.5f * w, py2 = cy + 0.5f * h;
            float a1 = (px2 - px1) * (py2 - py1);

            for (int t = 0; t < TN; ++t) {
                float pc = expf(L[slab[t]] - m) / s;   // L1/L2-warm gather
                float cb = fabsf(cx - tbr[t][0]) + fabsf(cy - tbr[t][1]);
                cb = cb + fabsf(w - tbr[t][2]);
                cb = cb + fabsf(h - tbr[t][3]);
                float ltx = fmaxf(px1, tbx[t][0]), lty = fmaxf(py1, tbx[t][1]);
                float rbx = fminf(px2, tbx[t][2]), rby = fminf(py2, tbx[t][3]);
                float wx = fmaxf(rbx - ltx, 0.f), wy = fmaxf(rby - lty, 0.f);
                float inter = wx * wy;
                float uni = a1 + tarea[t] - inter;
                float iou = inter / uni;
                float ex1 = fminf(px1, tbx[t][0]), ey1 = fminf(py1, tbx[t][1]);
                float ex2 = fmaxf(px2, tbx[t][2]), ey2 = fmaxf(py2, tbx[t][3]);
                float ew = fmaxf(ex2 - ex1, 0.f), eh = fmaxf(ey2 - ey1, 0.f);
                float ae = ew * eh;
                float giou = iou - (ae - uni) / ae;
                float cost = (-pc) + 5.0f * cb - 2.0f * giou;
                ben[t][q] = -cost;
                mn = fminf(mn, cost);
                mx = fmaxf(mx, cost);
            }
        }
    }

    // init price + sentinels
    for (int i = lane; i < BSTR; i += 64) price[i] = 0.f;
    if (lane < TN) {
        ben[lane][100] = -INFINITY; ben[lane][101] = -INFINITY;
        ben[lane][102] = -INFINITY; ben[lane][103] = -INFINITY;
    }
    __syncthreads();

    // eps (exact: spread = (-mn)-(-mx)+1e-6, /1000) — min/max order-free
    #pragma unroll
    for (int off = 32; off > 0; off >>= 1) {
        mn = fminf(mn, __shfl_xor(mn, off, 64));
        mx = fmaxf(mx, __shfl_xor(mx, off, 64));
    }
    const float eps = (((-mn) - (-mx)) + 1e-6f) / 1000.0f;

    // coalesced cost write-out from LDS
    {
        float4* dst = reinterpret_cast<float4*>(out_cost + (size_t)bf * (QN * TN));
        for (int i = lane; i < (QN * TN) / 4; i += 64) {
            int k = i * 4;
            int q = k / TN, t0 = k - q * TN;   // 20%4==0: never spans q
            float4 v;
            v.x = -ben[t0 + 0][q]; v.y = -ben[t0 + 1][q];
            v.z = -ben[t0 + 2][q]; v.w = -ben[t0 + 3][q];
            dst[i] = v;
        }
    }

    // ---- benefit chunks -> registers: lane = t*3 + j, chunks [0,36) [36,68) [68,104) ----
    const int myt = lane / 3;                  // 20,21 for lanes 60..63 (spectators)
    const int jj  = lane - myt * 3;
    const int q0  = (jj == 0) ? 0 : (jj == 1 ? 36 : 68);
    const bool is_leader = (lane < 60) && (jj == 0);
    float4 br[9];
    {
        const int tt = (lane < 60) ? myt : 0;
        const float4* rp = reinterpret_cast<const float4*>(&ben[tt][q0]);  // 416B rows, q0*4%16==0
        #pragma unroll
        for (int k = 0; k < 9; ++k) br[k] = rp[k];   // jj==1: k=8 in-bounds, unused
    }
    int myobj = -1;

    // one float4-step into chain X (strict > keeps lowest q on ties; tracks price at argmax)
    auto step4 = [&](T2& X, int fi) {
        float4 pv = *reinterpret_cast<const float4*>(&price[q0 + 4 * fi]);
        float4 bv = br[fi];
        { float v = bv.x - pv.x; bool c = v > X.v0; X.v1 = c ? X.v0 : fmaxf(X.v1, v); X.i0 = c ? (q0+4*fi+0) : X.i0; X.p0 = c ? pv.x : X.p0; X.v0 = c ? v : X.v0; }
        { float v = bv.y - pv.y; bool c = v > X.v0; X.v1 = c ? X.v0 : fmaxf(X.v1, v); X.i0 = c ? (q0+4*fi+1) : X.i0; X.p0 = c ? pv.y : X.p0; X.v0 = c ? v : X.v0; }
        { float v = bv.z - pv.z; bool c = v > X.v0; X.v1 = c ? X.v0 : fmaxf(X.v1, v); X.i0 = c ? (q0+4*fi+2) : X.i0; X.p0 = c ? pv.z : X.p0; X.v0 = c ? v : X.v0; }
        { float v = bv.w - pv.w; bool c = v > X.v0; X.v1 = c ? X.v0 : fmaxf(X.v1, v); X.i0 = c ? (q0+4*fi+3) : X.i0; X.p0 = c ? pv.w : X.p0; X.v0 = c ? v : X.v0; }
    };
    // ordered merge, left(lower q) favored on ties — identical to serial scan
    auto mergeT = [&](T2& L, const T2& R) {
        if (R.v0 > L.v0) { L.v1 = fmaxf(L.v0, R.v1); L.v0 = R.v0; L.i0 = R.i0; L.p0 = R.p0; }
        else             { L.v1 = fmaxf(R.v0, L.v1); }
    };

    // ---- auction: Jacobi, exact reference dynamics, 1 barrier/iter ----
    for (int it = 0; it < 20000; ++it) {
        const bool active = is_leader && (myobj < 0);
        unsigned long long U = __ballot(active);
        if (U == 0ull) break;

        // 3 contiguous ILP chains over my chunk
        T2 A{-INFINITY, -INFINITY, 0.f, q0};
        T2 Bc{-INFINITY, -INFINITY, 0.f, q0 + 12};
        T2 Cc{-INFINITY, -INFINITY, 0.f, q0 + 24};
        step4(A, 0);  step4(A, 1);  step4(A, 2);
        step4(Bc, 3); step4(Bc, 4); step4(Bc, 5);
        step4(Cc, 6); step4(Cc, 7);
        if (jj != 1) step4(Cc, 8);          // chunk widths 36/32/36 (sentinels at 100..103)
        mergeT(A, Bc); mergeT(A, Cc);

        // cross-lane ordered 3-way merge: leader pulls chunks j=1 (lane+1), j=2 (lane+2)
        {
            T2 R1{__shfl_down(A.v0, 1), __shfl_down(A.v1, 1), __shfl_down(A.p0, 1), __shfl_down(A.i0, 1)};
            T2 R2{__shfl_down(A.v0, 2), __shfl_down(A.v1, 2), __shfl_down(A.p0, 2), __shfl_down(A.i0, 2)};
            mergeT(A, R1); mergeT(A, R2);
        }
        float mybid = A.p0 + (A.v0 - A.v1) + eps;    // p0 == price[i0]; exact ref op order
        float bb_ = active ? mybid : -INFINITY;
        int   bq  = A.i0;

        // resolution entirely in registers: winner of q = max-(bid, -t) bidder on q;
        // an owner is evicted iff anyone bids on its object (that bidder's group has a winner).
        bool lose = false, evicted = false;
        if (__popcll(U) == 1) {
            int src = (int)__builtin_ctzll(U);       // sole bidder always wins
            int sq = __shfl(bq, src);
            evicted = (myobj == sq);
        } else {
            #pragma unroll
            for (int t2 = 0; t2 < TN; ++t2) {
                float sb = __shfl(bb_, 3 * t2);
                int   sq = __shfl(bq, 3 * t2);
                bool a2 = (sb != -INFINITY);
                lose    = lose    || (a2 && sq == bq   && (sb > bb_ || (sb == bb_ && t2 < myt)));
                evicted = evicted || (a2 && sq == myobj);
            }
        }
        if (active && !lose) { price[bq] = mybid; myobj = bq; }          // winners: distinct q
        else if (is_leader && evicted && myobj >= 0) myobj = -1;          // disjoint from winners
        __syncthreads();   // publish price updates for next iteration's scan
    }
    __syncthreads();
    if (is_leader) objl[myt] = myobj;
    __syncthreads();

    // ---- stable argsort of obj_of (rank computation) ----
    if (lane < TN) {
        int v = objl[lane];
        int r = 0;
        for (int u = 0; u < TN; ++u) {
            int w = objl[u];
            r += (w < v) || (w == v && u < lane);
        }
        out_pred[(size_t)bf * TN + r] = (float)v;
        out_tgt[(size_t)bf * TN + r]  = (float)lane;
    }
}

extern "C" void kernel_launch(void* const* d_in, const int* in_sizes, int n_in,
                              void* d_out, int out_size, void* d_ws, size_t ws_size,
                              hipStream_t stream) {
    const float* logits  = (const float*)d_in[0];
    const float* pboxes  = (const float*)d_in[1];
    const int*   tlabels = (const int*)d_in[2];
    const float* tboxes  = (const float*)d_in[3];

    float* out = (float*)d_out;
    float* out_cost = out;                                   // 64*36*100*20
    float* out_pred = out + (size_t)NB * NF * QN * TN;       // 64*36*20
    float* out_tgt  = out_pred + (size_t)NB * NF * TN;       // 64*36*20

    hipLaunchKernelGGL(matcher_kernel, dim3(NB * NF), dim3(64), 0, stream,
                       logits, pboxes, tlabels, tboxes, out_cost, out_pred, out_tgt);
}